// Round 6
// baseline (1550.516 us; speedup 1.0000x reference)
//
#include <hip/hip_runtime.h>
#include <cstdint>
#include <cstddef>

// ---------------------------------------------------------------------------
// BoxEmbeddingCBM: B=4096, F=2048, K=64, D=8, VOL_TEMP=0.5, INT_TEMP=0.1
//
// ROUND 5: identical compute pipeline to round 3 (simple f32 GEMM + literal
// fused_pair); outputs now written as FLOAT32 (H-f32-out). Inputs confirmed
// f32 in declared order by round-4 runtime detection.
// ws: Th 16 MB.
// ---------------------------------------------------------------------------

#define T_INT 0.1f
#define INV_T 10.0f

__device__ __forceinline__ float softplusf(float x) {
  return fmaxf(x, 0.0f) + log1pf(expf(-fabsf(x)));
}

// ---------------- G: simple tiled f32 GEMM, theta = feat@Wp + bp -----------
__global__ __launch_bounds__(256, 2) void gemm_simple(
    const float* __restrict__ A, const float* __restrict__ Wp,
    const float* __restrict__ bias, float* __restrict__ C) {
  __shared__ float As[32][68];  // [k][m]
  __shared__ float Bs[32][68];  // [k][n]
  const int t = threadIdx.x;
  const int m0 = blockIdx.x * 64, n0 = blockIdx.y * 64;
  const int tx = t & 15, ty = t >> 4;
  float acc[4][4] = {};

  for (int k0 = 0; k0 < 2048; k0 += 32) {
#pragma unroll
    for (int q = 0; q < 2; ++q) {
      const int idx = q * 256 + t;
      const int r = idx >> 3, c4 = (idx & 7) * 4;
      const float4 v = *reinterpret_cast<const float4*>(
          A + (size_t)(m0 + r) * 2048 + k0 + c4);
      As[c4 + 0][r] = v.x;
      As[c4 + 1][r] = v.y;
      As[c4 + 2][r] = v.z;
      As[c4 + 3][r] = v.w;
    }
#pragma unroll
    for (int q = 0; q < 2; ++q) {
      const int idx = q * 256 + t;
      const int fl = idx >> 4, ns = (idx & 15) * 4;
      const int n = n0 + ns;
      const float4 w = *reinterpret_cast<const float4*>(
          Wp + ((size_t)(n >> 4) * 2048 + k0 + fl) * 16 + (n & 15));
      *reinterpret_cast<float4*>(&Bs[fl][ns]) = w;
    }
    __syncthreads();
#pragma unroll 8
    for (int kk = 0; kk < 32; ++kk) {
      const float4 av = *reinterpret_cast<const float4*>(&As[kk][ty * 4]);
      const float4 bv = *reinterpret_cast<const float4*>(&Bs[kk][tx * 4]);
      const float a_[4] = {av.x, av.y, av.z, av.w};
      const float b_[4] = {bv.x, bv.y, bv.z, bv.w};
#pragma unroll
      for (int u = 0; u < 4; ++u)
#pragma unroll
        for (int v = 0; v < 4; ++v) acc[u][v] = fmaf(a_[u], b_[v], acc[u][v]);
    }
    __syncthreads();
  }
#pragma unroll
  for (int u = 0; u < 4; ++u) {
    const int row = m0 + ty * 4 + u;
#pragma unroll
    for (int v = 0; v < 4; ++v) {
      const int col = n0 + tx * 4 + v;
      C[(size_t)row * 1024 + col] = acc[u][v] + bias[col];
    }
  }
}

// ---------------- D: LITERAL fused boxes + probs + pairwise + final --------
__global__ __launch_bounds__(256, 2) void fused_pair(
    const float* __restrict__ Th, const float* __restrict__ Wprob,
    const float* __restrict__ bprob, const float* __restrict__ Wbox,
    const float* __restrict__ bbox, const float* __restrict__ Wrel,
    const float* __restrict__ brel, float* __restrict__ out) {
  __shared__ float sboxes[64][16];  // [k][0..7]=z, [8..15]=Z
  __shared__ float slvb[64];        // lv_box[k]
  __shared__ float spc[64];         // concept probs
  __shared__ float swrel[4096];
  __shared__ float swbox[1024];
  __shared__ float spart[256];

  const int b = blockIdx.x;
  const int t = threadIdx.x;
  const float* th = Th + (size_t)b * 1024;
  float* out_task = out;                 // [4096]
  float* out_conc = out + 4096;          // [4096][64]
  float* out_cond = out + 266240;        // [4096][64][64]

  if (t < 64) {
    const int k = t;
    float lvb = 0.0f;
    float logit = bprob[k];
#pragma unroll
    for (int d = 0; d < 8; ++d) {
      const float zd = th[k * 16 + d];
      const float w1 = th[k * 16 + 8 + d];
      const float Zd = zd + softplusf(w1);
      const float side = 0.5f * softplusf(2.0f * (Zd - zd));
      lvb += logf(fmaxf(side, 1e-23f));
      logit += zd * Wprob[k * 16 + d] + Zd * Wprob[k * 16 + 8 + d];
      sboxes[k][d] = zd;
      sboxes[k][8 + d] = Zd;
    }
    slvb[k] = lvb;
    const float pk = 1.0f / (1.0f + expf(-logit));
    spc[k] = pk;
    out_conc[(size_t)b * 64 + k] = pk;
  }
#pragma unroll
  for (int q = 0; q < 4; ++q)
    reinterpret_cast<float4*>(swrel)[q * 256 + t] =
        reinterpret_cast<const float4*>(Wrel)[q * 256 + t];
  reinterpret_cast<float4*>(swbox)[t] = reinterpret_cast<const float4*>(Wbox)[t];
  __syncthreads();

  const int wv = t >> 6, lane = t & 63;
  float zj[8], Zj[8];
#pragma unroll
  for (int d = 0; d < 8; ++d) {
    zj[d] = sboxes[lane][d];
    Zj[d] = sboxes[lane][8 + d];
  }
  const float lvbj = slvb[lane];
  float rsum = 0.0f;

  for (int ii = 0; ii < 16; ++ii) {
    const int i = wv * 16 + ii;
    float lvi = 0.0f;
#pragma unroll
    for (int d = 0; d < 8; ++d) {
      const float zi = sboxes[i][d], Zi = sboxes[i][8 + d];
      const float zjd = zj[d], Zjd = Zj[d];
      const float ai = zi * INV_T, aj = zjd * INV_T;
      float zint = T_INT * (fmaxf(ai, aj) + log1pf(expf(-fabsf(ai - aj))));
      zint = fmaxf(zint, fmaxf(zi, zjd));
      const float bi = -Zi * INV_T, bj = -Zjd * INV_T;
      float Zint = -T_INT * (fmaxf(bi, bj) + log1pf(expf(-fabsf(bi - bj))));
      Zint = fminf(Zint, fminf(Zi, Zjd));
      const float side = 0.5f * softplusf(2.0f * (Zint - zint));
      lvi += logf(fmaxf(side, 1e-23f));
    }
    float cond = expf(lvi - lvbj);
    cond = fminf(fmaxf(cond, 1e-6f), 1.0f - 1e-6f);
    out_cond[(size_t)b * 4096 + i * 64 + lane] = cond;
    rsum = fmaf(cond, swrel[i * 64 + lane], rsum);
  }

  float bsum = 0.0f;
#pragma unroll
  for (int q = 0; q < 4; ++q) {
    const int idx = t + 256 * q;
    const int k = idx >> 4, c = idx & 15;
    bsum = fmaf(sboxes[k][c] * spc[k], swbox[idx], bsum);
  }

  spart[t] = rsum + bsum;
  __syncthreads();
  for (int s = 128; s > 0; s >>= 1) {
    if (t < s) spart[t] += spart[t + s];
    __syncthreads();
  }
  if (t == 0) {
    const float s = spart[0] + bbox[0] + brel[0];
    out_task[b] = 1.0f / (1.0f + expf(-s));
  }
}

// ---------------------------------------------------------------------------
extern "C" void kernel_launch(void* const* d_in, const int* in_sizes, int n_in,
                              void* d_out, int out_size, void* d_ws, size_t ws_size,
                              hipStream_t stream) {
  const float* feat = (const float*)d_in[0];
  const float* Wp = (const float*)d_in[1];
  const float* bp = (const float*)d_in[2];
  const float* Wprob = (const float*)d_in[3];
  const float* bprob = (const float*)d_in[4];
  const float* Wbox = (const float*)d_in[5];
  const float* bbox = (const float*)d_in[6];
  const float* Wrel = (const float*)d_in[7];
  const float* brel = (const float*)d_in[8];
  float* out = (float*)d_out;

  float* Th = (float*)d_ws;  // 16 MB: [4096][1024] f32

  gemm_simple<<<dim3(64, 16), 256, 0, stream>>>(feat, Wp, bp, Th);
  fused_pair<<<4096, 256, 0, stream>>>(Th, Wprob, bprob, Wbox, bbox, Wrel, brel, out);
}

// Round 7
// 497.898 us; speedup vs baseline: 3.1141x; 3.1141x over previous
//
#include <hip/hip_runtime.h>
#include <cstdint>
#include <cstddef>

// ---------------------------------------------------------------------------
// BoxEmbeddingCBM: B=4096, F=2048, K=64, D=8, VOL_TEMP=0.5, INT_TEMP=0.1
//
// ROUND 6: fused_pair switched to log2-domain hw-transcendental math
// (3 v_exp + 2 v_log per pair-dim; algebra verified; degenerates to the
// same 1e-6 clip as the reference EPS path). gemm_simple unchanged.
// Outputs f32 (confirmed R5). ws: Th 16 MB.
// ---------------------------------------------------------------------------

#define LOG2E 1.4426950408889634f
#define LN2 0.6931471805599453f
#define K1C 14.426950408889634f  /* LOG2E / INT_TEMP */
#define K3C 2.8853900817779268f  /* 2*LOG2E  (vol beta = 1/VOL_TEMP = 2) */

__device__ __forceinline__ float ex2(float x) { return __builtin_exp2f(x); }
__device__ __forceinline__ float lg2(float x) { return __builtin_log2f(x); }

// ---------------- G: simple tiled f32 GEMM, theta = feat@Wp + bp -----------
__global__ __launch_bounds__(256, 2) void gemm_simple(
    const float* __restrict__ A, const float* __restrict__ Wp,
    const float* __restrict__ bias, float* __restrict__ C) {
  __shared__ float As[32][68];  // [k][m]
  __shared__ float Bs[32][68];  // [k][n]
  const int t = threadIdx.x;
  const int m0 = blockIdx.x * 64, n0 = blockIdx.y * 64;
  const int tx = t & 15, ty = t >> 4;
  float acc[4][4] = {};

  for (int k0 = 0; k0 < 2048; k0 += 32) {
#pragma unroll
    for (int q = 0; q < 2; ++q) {
      const int idx = q * 256 + t;
      const int r = idx >> 3, c4 = (idx & 7) * 4;
      const float4 v = *reinterpret_cast<const float4*>(
          A + (size_t)(m0 + r) * 2048 + k0 + c4);
      As[c4 + 0][r] = v.x;
      As[c4 + 1][r] = v.y;
      As[c4 + 2][r] = v.z;
      As[c4 + 3][r] = v.w;
    }
#pragma unroll
    for (int q = 0; q < 2; ++q) {
      const int idx = q * 256 + t;
      const int fl = idx >> 4, ns = (idx & 15) * 4;
      const int n = n0 + ns;
      const float4 w = *reinterpret_cast<const float4*>(
          Wp + ((size_t)(n >> 4) * 2048 + k0 + fl) * 16 + (n & 15));
      *reinterpret_cast<float4*>(&Bs[fl][ns]) = w;
    }
    __syncthreads();
#pragma unroll 8
    for (int kk = 0; kk < 32; ++kk) {
      const float4 av = *reinterpret_cast<const float4*>(&As[kk][ty * 4]);
      const float4 bv = *reinterpret_cast<const float4*>(&Bs[kk][tx * 4]);
      const float a_[4] = {av.x, av.y, av.z, av.w};
      const float b_[4] = {bv.x, bv.y, bv.z, bv.w};
#pragma unroll
      for (int u = 0; u < 4; ++u)
#pragma unroll
        for (int v = 0; v < 4; ++v) acc[u][v] = fmaf(a_[u], b_[v], acc[u][v]);
    }
    __syncthreads();
  }
#pragma unroll
  for (int u = 0; u < 4; ++u) {
    const int row = m0 + ty * 4 + u;
#pragma unroll
    for (int v = 0; v < 4; ++v) {
      const int col = n0 + tx * 4 + v;
      C[(size_t)row * 1024 + col] = acc[u][v] + bias[col];
    }
  }
}

// ---------------- D: fast fused boxes + probs + pairwise + final -----------
__global__ __launch_bounds__(256, 2) void fused_pair(
    const float* __restrict__ Th, const float* __restrict__ Wprob,
    const float* __restrict__ bprob, const float* __restrict__ Wbox,
    const float* __restrict__ bbox, const float* __restrict__ Wrel,
    const float* __restrict__ brel, float* __restrict__ out) {
  __shared__ float sboxes[64][16];  // [k][0..7]=z, [8..15]=Z
  __shared__ float spinv[64];       // 1 / prod_d log2(1+exp2(K3*(Z-z)))
  __shared__ float spc[64];         // concept probs
  __shared__ float swrel[4096];
  __shared__ float swbox[1024];
  __shared__ float sred[4];

  const int b = blockIdx.x;
  const int t = threadIdx.x;
  const float* th = Th + (size_t)b * 1024;
  float* out_task = out;           // [4096]
  float* out_conc = out + 4096;    // [4096][64]
  float* out_cond = out + 266240;  // [4096][64][64]

  if (t < 64) {
    const int k = t;
    const float* thk = th + k * 16;
    float4 a0 = reinterpret_cast<const float4*>(thk)[0];
    float4 a1 = reinterpret_cast<const float4*>(thk)[1];
    float4 a2 = reinterpret_cast<const float4*>(thk)[2];
    float4 a3 = reinterpret_cast<const float4*>(thk)[3];
    float z[8] = {a0.x, a0.y, a0.z, a0.w, a1.x, a1.y, a1.z, a1.w};
    float w1[8] = {a2.x, a2.y, a2.z, a2.w, a3.x, a3.y, a3.z, a3.w};
    float dp = 1.0f;
    float logit = bprob[k];
#pragma unroll
    for (int d = 0; d < 8; ++d) {
      // softplus(x) = ln2 * log2(1 + 2^(x*log2e)); x ~ N(0,1): no overflow
      const float spv = LN2 * lg2(1.0f + ex2(w1[d] * LOG2E));
      const float Zd = z[d] + spv;
      const float denl = lg2(1.0f + ex2((Zd - z[d]) * K3C));  // >= 1
      dp *= denl;
      logit += z[d] * Wprob[k * 16 + d] + Zd * Wprob[k * 16 + 8 + d];
      sboxes[k][d] = z[d];
      sboxes[k][8 + d] = Zd;
    }
    spinv[k] = 1.0f / dp;
    const float pk = 1.0f / (1.0f + ex2(-logit * LOG2E));
    spc[k] = pk;
    out_conc[(size_t)b * 64 + k] = pk;
  }
#pragma unroll
  for (int q = 0; q < 4; ++q)
    reinterpret_cast<float4*>(swrel)[q * 256 + t] =
        reinterpret_cast<const float4*>(Wrel)[q * 256 + t];
  reinterpret_cast<float4*>(swbox)[t] = reinterpret_cast<const float4*>(Wbox)[t];
  __syncthreads();

  const int wv = t >> 6, lane = t & 63;
  float zj[8], Zj[8];
#pragma unroll
  for (int d = 0; d < 8; ++d) {
    zj[d] = sboxes[lane][d];
    Zj[d] = sboxes[lane][8 + d];
  }
  const float pinvj = spinv[lane];
  float rsum = 0.0f;

  for (int ii = 0; ii < 16; ++ii) {
    const int i = wv * 16 + ii;
    float prodn = 1.0f;
#pragma unroll
    for (int d = 0; d < 8; ++d) {
      const float zi = sboxes[i][d], Zi = sboxes[i][8 + d];
      // u = exp(-|dz|/t), uZ = exp(-|dZ|/t)  (as exp2)
      const float u = ex2(-fabsf(zi - zj[d]) * K1C);
      const float uZ = ex2(-fabsf(Zi - Zj[d]) * K1C);
      // log2((1+u)(1+uZ)) in one log
      const float lsum = lg2(fmaf(u, uZ, 1.0f + u + uZ));
      const float gap = fminf(Zi, Zj[d]) - fmaxf(zi, zj[d]);
      // E = exp(2*(Z_int - z_int)) = 2^(gap*2*log2e - 2*t*lsum)
      const float E = ex2(fmaf(gap, K3C, -0.2f * lsum));
      prodn *= lg2(1.0f + E);
    }
    float cond = prodn * pinvj;  // (ln2/2)^8 cancels in the ratio
    cond = fminf(fmaxf(cond, 1e-6f), 1.0f - 1e-6f);
    out_cond[(size_t)b * 4096 + i * 64 + lane] = cond;
    rsum = fmaf(cond, swrel[i * 64 + lane], rsum);
  }

  float bsum = 0.0f;
#pragma unroll
  for (int q = 0; q < 4; ++q) {
    const int idx = t + 256 * q;
    const int k = idx >> 4, c = idx & 15;
    bsum = fmaf(sboxes[k][c] * spc[k], swbox[idx], bsum);
  }
  float total = rsum + bsum;
#pragma unroll
  for (int off = 32; off > 0; off >>= 1) total += __shfl_down(total, off, 64);
  if (lane == 0) sred[wv] = total;
  __syncthreads();
  if (t == 0) {
    const float s = sred[0] + sred[1] + sred[2] + sred[3] + bbox[0] + brel[0];
    out_task[b] = 1.0f / (1.0f + ex2(-s * LOG2E));
  }
}

// ---------------------------------------------------------------------------
extern "C" void kernel_launch(void* const* d_in, const int* in_sizes, int n_in,
                              void* d_out, int out_size, void* d_ws, size_t ws_size,
                              hipStream_t stream) {
  const float* feat = (const float*)d_in[0];
  const float* Wp = (const float*)d_in[1];
  const float* bp = (const float*)d_in[2];
  const float* Wprob = (const float*)d_in[3];
  const float* bprob = (const float*)d_in[4];
  const float* Wbox = (const float*)d_in[5];
  const float* bbox = (const float*)d_in[6];
  const float* Wrel = (const float*)d_in[7];
  const float* brel = (const float*)d_in[8];
  float* out = (float*)d_out;

  float* Th = (float*)d_ws;  // 16 MB: [4096][1024] f32

  gemm_simple<<<dim3(64, 16), 256, 0, stream>>>(feat, Wp, bp, Th);
  fused_pair<<<4096, 256, 0, stream>>>(Th, Wprob, bprob, Wbox, bbox, Wrel, brel, out);
}

// Round 8
// 286.845 us; speedup vs baseline: 5.4054x; 1.7358x over previous
//
#include <hip/hip_runtime.h>
#include <cstdint>
#include <cstddef>

// ---------------------------------------------------------------------------
// BoxEmbeddingCBM: B=4096, F=2048, K=64, D=8, VOL_TEMP=0.5, INT_TEMP=0.1
//
// ROUND 7:
//   - GEMM -> 3-term split-bf16 MFMA (structure validated in R1: R1==R2),
//     A split hi/lo during LDS staging; B pre-split by prep_b (grid 64x16).
//   - fused_pair -> symmetric-numerator: phase A computes 2080 unique
//     prodn values (upper triangle) into LDS; phase B reuses them for all
//     64x64 ordered pairs with coalesced stores.
// Outputs f32. ws: Bt 8 MB + Th 16 MB = 24 MB (proven safe).
// ---------------------------------------------------------------------------

typedef __bf16 bf16_t;
typedef __bf16 bf16x4 __attribute__((ext_vector_type(4)));
typedef __bf16 bf16x8 __attribute__((ext_vector_type(8)));
typedef float floatx4 __attribute__((ext_vector_type(4)));

#define LOG2E 1.4426950408889634f
#define LN2 0.6931471805599453f
#define K1C 14.426950408889634f  /* LOG2E / INT_TEMP */
#define K3C 2.8853900817779268f  /* 2*LOG2E  (vol beta = 1/VOL_TEMP = 2) */

__device__ __forceinline__ float ex2(float x) { return __builtin_exp2f(x); }
__device__ __forceinline__ float lg2(float x) { return __builtin_log2f(x); }

// ---------------- P2: transpose+split Wp into Bt [1024][4096] --------------
// row n = kc*16+d; cols 0..2047 = hi(bf16), 2048..4095 = lo(bf16)
__global__ __launch_bounds__(256, 2) void prep_b(const float* __restrict__ Wp,
                                                 bf16_t* __restrict__ Bt) {
  __shared__ float tile[128][17];
  const int kc = blockIdx.x;       // concept 0..63
  const int f0 = blockIdx.y * 128; // feature chunk
  const int t = threadIdx.x;
  {
    const int fl = t >> 1, dh = (t & 1) * 8;
    const float* g = Wp + ((size_t)kc * 2048 + f0 + fl) * 16 + dh;
    float4 v0 = *reinterpret_cast<const float4*>(g);
    float4 v1 = *reinterpret_cast<const float4*>(g + 4);
    tile[fl][dh + 0] = v0.x; tile[fl][dh + 1] = v0.y;
    tile[fl][dh + 2] = v0.z; tile[fl][dh + 3] = v0.w;
    tile[fl][dh + 4] = v1.x; tile[fl][dh + 5] = v1.y;
    tile[fl][dh + 6] = v1.z; tile[fl][dh + 7] = v1.w;
  }
  __syncthreads();
  {
    const int d = t >> 4, fi = (t & 15) * 8;
    float x[8];
#pragma unroll
    for (int u = 0; u < 8; ++u) x[u] = tile[fi + u][d];
    bf16x8 hv, lv;
#pragma unroll
    for (int u = 0; u < 8; ++u) {
      __bf16 h = (__bf16)x[u];
      hv[u] = h;
      lv[u] = (__bf16)(x[u] - (float)h);
    }
    const size_t row = (size_t)(kc * 16 + d) * 4096;
    *reinterpret_cast<bf16x8*>(Bt + row + f0 + fi) = hv;
    *reinterpret_cast<bf16x8*>(Bt + row + 2048 + f0 + fi) = lv;
  }
}

// ---------------- G: split-bf16 MFMA GEMM, theta = feat@Wp + bp ------------
// BM=128, BN=64, BK=32; 4 waves 2x2; wave tile 64x32 (4x2 frags), 3 MFMAs
// per frag pair (hh + lh + hl). A split during staging.
__global__ __launch_bounds__(256, 2) void gemm_theta(
    const float* __restrict__ A, const bf16_t* __restrict__ Bt,
    const float* __restrict__ bias, float* __restrict__ C) {
  __shared__ bf16_t Ah[128][40];
  __shared__ bf16_t Al[128][40];
  __shared__ bf16_t Bh[64][40];
  __shared__ bf16_t Bl[64][40];
  const int t = threadIdx.x;
  const int m0 = blockIdx.x * 128, n0 = blockIdx.y * 64;
  const int wave = t >> 6, lane = t & 63, quad = lane >> 4, l16 = lane & 15;
  const int wm = (wave >> 1) * 64, wn = (wave & 1) * 32;
  floatx4 acc[4][2] = {};
  const int rB = t >> 2, cB = (t & 3) * 8;

  for (int kk = 0; kk < 64; ++kk) {
    const int k = kk * 32;
    // stage A: 128x32 f32 -> hi/lo bf16 (split once per tile)
#pragma unroll
    for (int q = 0; q < 4; ++q) {
      const int idx = q * 256 + t;
      const int r = idx >> 3, c4 = (idx & 7) * 4;
      const float4 v = *reinterpret_cast<const float4*>(
          A + (size_t)(m0 + r) * 2048 + k + c4);
      bf16x4 hv = {(__bf16)v.x, (__bf16)v.y, (__bf16)v.z, (__bf16)v.w};
      bf16x4 lv = {(__bf16)(v.x - (float)hv[0]), (__bf16)(v.y - (float)hv[1]),
                   (__bf16)(v.z - (float)hv[2]), (__bf16)(v.w - (float)hv[3])};
      *reinterpret_cast<bf16x4*>(&Ah[r][c4]) = hv;
      *reinterpret_cast<bf16x4*>(&Al[r][c4]) = lv;
    }
    // stage B hi/lo (pre-split in Bt)
    {
      const bf16_t* src = Bt + (size_t)(n0 + rB) * 4096 + k + cB;
      *reinterpret_cast<bf16x8*>(&Bh[rB][cB]) =
          *reinterpret_cast<const bf16x8*>(src);
      *reinterpret_cast<bf16x8*>(&Bl[rB][cB]) =
          *reinterpret_cast<const bf16x8*>(src + 2048);
    }
    __syncthreads();
    bf16x8 ah[4], al[4], bh[2], bl[2];
#pragma unroll
    for (int r = 0; r < 4; ++r) {
      ah[r] = *reinterpret_cast<const bf16x8*>(&Ah[wm + r * 16 + l16][quad * 8]);
      al[r] = *reinterpret_cast<const bf16x8*>(&Al[wm + r * 16 + l16][quad * 8]);
    }
#pragma unroll
    for (int c = 0; c < 2; ++c) {
      bh[c] = *reinterpret_cast<const bf16x8*>(&Bh[wn + c * 16 + l16][quad * 8]);
      bl[c] = *reinterpret_cast<const bf16x8*>(&Bl[wn + c * 16 + l16][quad * 8]);
    }
#pragma unroll
    for (int r = 0; r < 4; ++r)
#pragma unroll
      for (int c = 0; c < 2; ++c) {
        acc[r][c] =
            __builtin_amdgcn_mfma_f32_16x16x32_bf16(ah[r], bh[c], acc[r][c], 0, 0, 0);
        acc[r][c] =
            __builtin_amdgcn_mfma_f32_16x16x32_bf16(al[r], bh[c], acc[r][c], 0, 0, 0);
        acc[r][c] =
            __builtin_amdgcn_mfma_f32_16x16x32_bf16(ah[r], bl[c], acc[r][c], 0, 0, 0);
      }
    __syncthreads();
  }
  // epilogue: C/D layout col=lane&15 (N), row=quad*4+i (M)
#pragma unroll
  for (int r = 0; r < 4; ++r) {
    const int row0 = m0 + wm + r * 16 + quad * 4;
#pragma unroll
    for (int c = 0; c < 2; ++c) {
      const int col = n0 + wn + c * 16 + l16;
      const float bb = bias[col];
#pragma unroll
      for (int i = 0; i < 4; ++i)
        C[(size_t)(row0 + i) * 1024 + col] = acc[r][c][i] + bb;
    }
  }
}

// ---------------- D: fused boxes + probs + pairwise (symmetric) + final ----
__global__ __launch_bounds__(256, 2) void fused_pair(
    const float* __restrict__ Th, const float* __restrict__ Wprob,
    const float* __restrict__ bprob, const float* __restrict__ Wbox,
    const float* __restrict__ bbox, const float* __restrict__ Wrel,
    const float* __restrict__ brel, float* __restrict__ out) {
  __shared__ float sboxes[64][17];  // pad 17: scattered row reads conflict-free
  __shared__ float spinv[64];       // 1 / prod_d log2(1+exp2(K3*(Z-z)))
  __shared__ float spc[64];
  __shared__ float swrel[4096];
  __shared__ float swbox[1024];
  __shared__ float sprod[2080];     // upper-triangle numerators (i<=j)
  __shared__ float sred[4];

  const int b = blockIdx.x;
  const int t = threadIdx.x;
  const float* th = Th + (size_t)b * 1024;
  float* out_task = out;           // [4096]
  float* out_conc = out + 4096;    // [4096][64]
  float* out_cond = out + 266240;  // [4096][64][64]

  if (t < 64) {
    const int k = t;
    const float* thk = th + k * 16;
    float4 a0 = reinterpret_cast<const float4*>(thk)[0];
    float4 a1 = reinterpret_cast<const float4*>(thk)[1];
    float4 a2 = reinterpret_cast<const float4*>(thk)[2];
    float4 a3 = reinterpret_cast<const float4*>(thk)[3];
    float z[8] = {a0.x, a0.y, a0.z, a0.w, a1.x, a1.y, a1.z, a1.w};
    float w1[8] = {a2.x, a2.y, a2.z, a2.w, a3.x, a3.y, a3.z, a3.w};
    float dp = 1.0f;
    float logit = bprob[k];
#pragma unroll
    for (int d = 0; d < 8; ++d) {
      const float spv = LN2 * lg2(1.0f + ex2(w1[d] * LOG2E));  // softplus
      const float Zd = z[d] + spv;
      const float denl = lg2(1.0f + ex2((Zd - z[d]) * K3C));   // >= 1
      dp *= denl;
      logit += z[d] * Wprob[k * 16 + d] + Zd * Wprob[k * 16 + 8 + d];
      sboxes[k][d] = z[d];
      sboxes[k][8 + d] = Zd;
    }
    spinv[k] = 1.0f / dp;
    const float pk = 1.0f / (1.0f + ex2(-logit * LOG2E));
    spc[k] = pk;
    out_conc[(size_t)b * 64 + k] = pk;
  }
#pragma unroll
  for (int q = 0; q < 4; ++q)
    reinterpret_cast<float4*>(swrel)[q * 256 + t] =
        reinterpret_cast<const float4*>(Wrel)[q * 256 + t];
  reinterpret_cast<float4*>(swbox)[t] = reinterpret_cast<const float4*>(Wbox)[t];
  __syncthreads();

  // ---- phase A: unique numerators over the 2080 (i<=j) pairs ----
#pragma unroll
  for (int q = 0; q < 9; ++q) {
    const int p = t + 256 * q;
    if (p < 2080) {
      int j = (int)((sqrtf((float)(8 * p + 1)) - 1.0f) * 0.5f);
      if ((j + 1) * (j + 2) / 2 <= p) ++j;
      if (j * (j + 1) / 2 > p) --j;
      const int i = p - j * (j + 1) / 2;  // i <= j
      float prodn = 1.0f;
#pragma unroll
      for (int d = 0; d < 8; ++d) {
        const float zi = sboxes[i][d], Zi = sboxes[i][8 + d];
        const float zjd = sboxes[j][d], Zjd = sboxes[j][8 + d];
        const float u = ex2(-fabsf(zi - zjd) * K1C);
        const float uZ = ex2(-fabsf(Zi - Zjd) * K1C);
        const float lsum = lg2(fmaf(u, uZ, 1.0f + u + uZ));
        const float gap = fminf(Zi, Zjd) - fmaxf(zi, zjd);
        const float E = ex2(fmaf(gap, K3C, -0.2f * lsum));
        prodn *= lg2(1.0f + E);
      }
      sprod[p] = prodn;
    }
  }
  __syncthreads();

  // ---- phase B: expand to ordered pairs, coalesced stores ----
  const int wv = t >> 6, lane = t & 63;
  const float pinvj = spinv[lane];
  float rsum = 0.0f;
#pragma unroll 4
  for (int ii = 0; ii < 16; ++ii) {
    const int i = wv * 16 + ii;
    const int lo = min(i, lane), hi = max(i, lane);
    const float prodn = sprod[hi * (hi + 1) / 2 + lo];
    float cond = prodn * pinvj;
    cond = fminf(fmaxf(cond, 1e-6f), 1.0f - 1e-6f);
    out_cond[(size_t)b * 4096 + i * 64 + lane] = cond;
    rsum = fmaf(cond, swrel[i * 64 + lane], rsum);
  }

  float bsum = 0.0f;
#pragma unroll
  for (int q = 0; q < 4; ++q) {
    const int idx = t + 256 * q;
    const int k = idx >> 4, c = idx & 15;
    bsum = fmaf(sboxes[k][c] * spc[k], swbox[idx], bsum);
  }
  float total = rsum + bsum;
#pragma unroll
  for (int off = 32; off > 0; off >>= 1) total += __shfl_down(total, off, 64);
  if (lane == 0) sred[wv] = total;
  __syncthreads();
  if (t == 0) {
    const float s = sred[0] + sred[1] + sred[2] + sred[3] + bbox[0] + brel[0];
    out_task[b] = 1.0f / (1.0f + ex2(-s * LOG2E));
  }
}

// ---------------------------------------------------------------------------
extern "C" void kernel_launch(void* const* d_in, const int* in_sizes, int n_in,
                              void* d_out, int out_size, void* d_ws, size_t ws_size,
                              hipStream_t stream) {
  const float* feat = (const float*)d_in[0];
  const float* Wp = (const float*)d_in[1];
  const float* bp = (const float*)d_in[2];
  const float* Wprob = (const float*)d_in[3];
  const float* bprob = (const float*)d_in[4];
  const float* Wbox = (const float*)d_in[5];
  const float* bbox = (const float*)d_in[6];
  const float* Wrel = (const float*)d_in[7];
  const float* brel = (const float*)d_in[8];
  float* out = (float*)d_out;

  char* ws = (char*)d_ws;
  bf16_t* Bt = (bf16_t*)ws;                      //  8 MB: [1024][4096] bf16
  float* Th = (float*)(ws + (size_t)(8 << 20));  // 16 MB: [4096][1024] f32

  prep_b<<<dim3(64, 16), 256, 0, stream>>>(Wp, Bt);
  gemm_theta<<<dim3(32, 16), 256, 0, stream>>>(feat, Bt, bp, Th);
  fused_pair<<<4096, 256, 0, stream>>>(Th, Wprob, bprob, Wbox, bbox, Wrel, brel, out);
}